// Round 10
// baseline (133.319 us; speedup 1.0000x reference)
//
#include <hip/hip_runtime.h>

// Sparse voxel downsample (FACTOR=2, RES=256 -> res=128, B=2, C=64).
// code = ((b*128 + x/2)*128 + y/2)*128 + z/2  in [0, 4194304)
// u8 dense histogram + 2-level FLAG scan -> sorted rank per occupied code
// (== jnp.unique inverse, ascending codes, padding at end). Rank+count are
// recomputed per input from cnt8+wprefix (4.2MB L2/L3-hot) -- no rank table,
// no counting sort. Hot pass is a SCATTER (random writes don't stall):
// sequential feats read, plain NT store for singleton rows (~94%),
// atomicAdd(v/cnt) into pre-zeroed rows for the rest.

#define RES2 128
#define NCODES (2 * 128 * 128 * 128)   // 4194304 codes
#define NW (NCODES / 4)                // u32 words in u8 histogram
#define HBLK 4096                      // NW/256 blocks over word space

typedef float f4 __attribute__((ext_vector_type(4)));

__global__ void count_codes(const int* __restrict__ coords,
                            unsigned* __restrict__ cnt8,
                            int* __restrict__ codes, int n) {
    int i = blockIdx.x * 256 + threadIdx.x;
    if (i >= n) return;
    const int4 v = reinterpret_cast<const int4*>(coords)[i];
    int code = (((v.x * RES2 + (v.y >> 1)) * RES2 + (v.z >> 1)) * RES2) + (v.w >> 1);
    codes[i] = code;
    atomicAdd(&cnt8[code >> 2], 1u << (8 * (code & 3)));   // u8 lanes, max ~9
}

// Per block of 256 words (1024 codes): count of occupied codes.
__global__ void block_flag_sum(const unsigned* __restrict__ cnt8,
                               unsigned* __restrict__ btot) {
    __shared__ unsigned sh[256];
    int t = threadIdx.x;
    unsigned w = cnt8[blockIdx.x * 256 + t];
    sh[t] = ((w & 0xFFu) != 0) + (((w >> 8) & 0xFFu) != 0) +
            (((w >> 16) & 0xFFu) != 0) + ((w >> 24) != 0);
    __syncthreads();
    for (int off = 128; off > 0; off >>= 1) {
        if (t < off) sh[t] += sh[t + off];
        __syncthreads();
    }
    if (t == 0) btot[blockIdx.x] = sh[0];
}

// Single block: exclusive scan over 4096 block totals; n_unique -> *nuq.
__global__ void scan_totals(unsigned* __restrict__ btot,
                            unsigned* __restrict__ nuq) {
    __shared__ unsigned sh[1024];
    int t = threadIdx.x;
    int base = t * 4;
    unsigned v[4], e[4], s = 0;
#pragma unroll
    for (int j = 0; j < 4; ++j) { v[j] = btot[base + j]; e[j] = s; s += v[j]; }
    sh[t] = s;
    __syncthreads();
    for (int off = 1; off < 1024; off <<= 1) {
        unsigned add = (t >= off) ? sh[t - off] : 0u;
        __syncthreads();
        sh[t] += add;
        __syncthreads();
    }
    unsigned excl = (t == 0) ? 0u : sh[t - 1];
#pragma unroll
    for (int j = 0; j < 4; ++j) btot[base + j] = excl + e[j];
    if (t == 1023) *nuq = sh[1023];
}

// Second flag pass: wprefix[word] = #occupied codes before this word
// (sequential 4.2MB write). Per occupied code: write decoded coords at row
// rank; zero outF rows with count>=2 (singletons get plain stores later).
__global__ void scan_write(const unsigned* __restrict__ cnt8,
                           const unsigned* __restrict__ btot,
                           unsigned* __restrict__ wprefix,
                           f4* __restrict__ outF4,
                           f4* __restrict__ outC4) {
    __shared__ unsigned sh[256];
    int t = threadIdx.x;
    int widx = blockIdx.x * 256 + t;
    unsigned w = cnt8[widx];
    unsigned c4[4] = {w & 0xFFu, (w >> 8) & 0xFFu, (w >> 16) & 0xFFu, w >> 24};
    unsigned e[4], s = 0;
#pragma unroll
    for (int j = 0; j < 4; ++j) { e[j] = s; s += (c4[j] != 0); }
    sh[t] = s;
    __syncthreads();
    for (int off = 1; off < 256; off <<= 1) {
        unsigned add = (t >= off) ? sh[t - off] : 0u;
        __syncthreads();
        sh[t] += add;
        __syncthreads();
    }
    unsigned texcl = ((t == 0) ? 0u : sh[t - 1]) + btot[blockIdx.x];
    wprefix[widx] = texcl;
    int cbase = widx * 4;
#pragma unroll
    for (int j = 0; j < 4; ++j) {
        if (c4[j]) {
            unsigned r = texcl + e[j];   // e[j] is the within-word exclusive rank
            int code = cbase + j;
            f4 cv = {(float)(code >> 21), (float)((code >> 14) & 127),
                     (float)((code >> 7) & 127), (float)(code & 127)};
            outC4[r] = cv;
            if (c4[j] >= 2) {
                f4* row = outF4 + (size_t)r * 16;
                const f4 zz = {0.f, 0.f, 0.f, 0.f};
#pragma unroll
                for (int q = 0; q < 16; ++q) row[q] = zz;
            }
        }
    }
}

// Padding rows [n_uniq, n): zero feats, coords = -1.
__global__ void tail_pad(const unsigned* __restrict__ nuq,
                         f4* __restrict__ outF4,
                         f4* __restrict__ outC4, int n) {
    int r = blockIdx.x * 256 + threadIdx.x;
    if (r >= n || r < (int)*nuq) return;
    f4* row = outF4 + (size_t)r * 16;
    const f4 zz = {0.f, 0.f, 0.f, 0.f};
#pragma unroll
    for (int q = 0; q < 16; ++q) row[q] = zz;
    f4 mm = {-1.f, -1.f, -1.f, -1.f};
    outC4[r] = mm;
}

// Hot pass: 8 input rows per wave (quarter-wave = one 256B row, 2 batches).
// Sequential feats read; random 256B NT stores (fire-and-forget) for
// singleton rows, atomicAdd(v/cnt) for shared rows.
__global__ void scatter8(const f4* __restrict__ feats4,
                         const int* __restrict__ codes,
                         const unsigned* __restrict__ cnt8,
                         const unsigned* __restrict__ wprefix,
                         f4* __restrict__ outF4, int n) {
    int tid = blockIdx.x * 256 + threadIdx.x;
    int lane = threadIdx.x & 63;
    int wave = tid >> 6;
    int q = lane >> 4;
    int sub = lane & 15;
    int ib = wave * 8;

#pragma unroll
    for (int h = 0; h < 2; ++h) {
        int i = ib + h * 4 + q;
        if (i >= n) continue;
        int c = codes[i];
        unsigned w = cnt8[c >> 2];
        unsigned base = wprefix[c >> 2];
        int j = c & 3;
        unsigned cnt = (w >> (8 * j)) & 0xFFu;
        unsigned occ = 0;
        if (j > 0) occ += ((w & 0xFFu) != 0);
        if (j > 1) occ += (((w >> 8) & 0xFFu) != 0);
        if (j > 2) occ += (((w >> 16) & 0xFFu) != 0);
        unsigned r = base + occ;
        f4 v = feats4[(size_t)i * 16 + sub];
        f4* dst = outF4 + (size_t)r * 16 + sub;
        if (cnt == 1) {
            __builtin_nontemporal_store(v, dst);
        } else {
            float sc = 1.0f / (float)cnt;
            float* d = (float*)dst;
            atomicAdd(d + 0, v.x * sc);
            atomicAdd(d + 1, v.y * sc);
            atomicAdd(d + 2, v.z * sc);
            atomicAdd(d + 3, v.w * sc);
        }
    }
}

extern "C" void kernel_launch(void* const* d_in, const int* in_sizes, int n_in,
                              void* d_out, int out_size, void* d_ws, size_t ws_size,
                              hipStream_t stream) {
    const float* feats = (const float*)d_in[0];
    const int* coords = (const int*)d_in[1];
    const int n = in_sizes[1] / 4;   // N = 500000

    float* outF = (float*)d_out;
    f4* outF4 = (f4*)outF;
    f4* outC4 = (f4*)(outF + (size_t)n * 64);

    unsigned* cnt8 = (unsigned*)d_ws;              // NW u32 (4.19 MB)
    unsigned* btot = cnt8 + NW;                    // 4096
    unsigned* nuq = btot + HBLK;                   // 1
    int* codes = (int*)(nuq + 1);                  // n
    unsigned* wprefix = (unsigned*)(codes + n);    // NW u32 (4.19 MB)

    (void)hipMemsetAsync(cnt8, 0, (size_t)NW * sizeof(unsigned), stream);

    count_codes<<<(n + 255) / 256, 256, 0, stream>>>(coords, cnt8, codes, n);
    block_flag_sum<<<HBLK, 256, 0, stream>>>(cnt8, btot);
    scan_totals<<<1, 1024, 0, stream>>>(btot, nuq);
    scan_write<<<HBLK, 256, 0, stream>>>(cnt8, btot, wprefix, outF4, outC4);
    tail_pad<<<(n + 255) / 256, 256, 0, stream>>>(nuq, outF4, outC4, n);

    int waves = (n + 7) / 8;
    int blocks = (waves * 64 + 255) / 256;
    scatter8<<<blocks, 256, 0, stream>>>((const f4*)feats, codes, cnt8,
                                         wprefix, outF4, n);
}

// Round 11
// 133.194 us; speedup vs baseline: 1.0009x; 1.0009x over previous
//
#include <hip/hip_runtime.h>

// Sparse voxel downsample (FACTOR=2, RES=256 -> res=128, B=2, C=64).
// code = ((b*128 + x/2)*128 + y/2)*128 + z/2  in [0, 4194304)
// u8 dense histogram + 2-level FLAG scan -> sorted rank per occupied code
// (== jnp.unique inverse, ascending codes, padding at end). Rank+count are
// recomputed per input from cnt8+wprefix (4.2MB L2/L3-hot) -- no rank table,
// no counting sort. Hot pass is a SCATTER (random writes don't stall):
// sequential feats read, plain NT store for singleton rows (~94%),
// atomicAdd(v/cnt) into pre-zeroed rows for the rest.
// cnt8 is zeroed by a custom wide-store kernel: the runtime's
// fillBufferAligned handled the 4.19MB memset at 53 GB/s (80us in-graph!).

#define RES2 128
#define NCODES (2 * 128 * 128 * 128)   // 4194304 codes
#define NW (NCODES / 4)                // u32 words in u8 histogram
#define HBLK 4096                      // NW/256 blocks over word space

typedef float f4 __attribute__((ext_vector_type(4)));

// Zero NW u32 words (4.19 MB) with uint4 stores; 2048 blocks x 256 thr.
__global__ void zero_cnt(uint4* __restrict__ p) {
    int i = blockIdx.x * 256 + threadIdx.x;
    const uint4 zz = make_uint4(0u, 0u, 0u, 0u);
    // NW/4 = 262144 uint4 words; 2048*256 = 524288 threads -> 1 store each
    if (i < NW / 4) p[i] = zz;
}

__global__ void count_codes(const int* __restrict__ coords,
                            unsigned* __restrict__ cnt8,
                            int* __restrict__ codes, int n) {
    int i = blockIdx.x * 256 + threadIdx.x;
    if (i >= n) return;
    const int4 v = reinterpret_cast<const int4*>(coords)[i];
    int code = (((v.x * RES2 + (v.y >> 1)) * RES2 + (v.z >> 1)) * RES2) + (v.w >> 1);
    codes[i] = code;
    atomicAdd(&cnt8[code >> 2], 1u << (8 * (code & 3)));   // u8 lanes, max ~9
}

// Per block of 256 words (1024 codes): count of occupied codes.
__global__ void block_flag_sum(const unsigned* __restrict__ cnt8,
                               unsigned* __restrict__ btot) {
    __shared__ unsigned sh[256];
    int t = threadIdx.x;
    unsigned w = cnt8[blockIdx.x * 256 + t];
    sh[t] = ((w & 0xFFu) != 0) + (((w >> 8) & 0xFFu) != 0) +
            (((w >> 16) & 0xFFu) != 0) + ((w >> 24) != 0);
    __syncthreads();
    for (int off = 128; off > 0; off >>= 1) {
        if (t < off) sh[t] += sh[t + off];
        __syncthreads();
    }
    if (t == 0) btot[blockIdx.x] = sh[0];
}

// Single block: exclusive scan over 4096 block totals; n_unique -> *nuq.
__global__ void scan_totals(unsigned* __restrict__ btot,
                            unsigned* __restrict__ nuq) {
    __shared__ unsigned sh[1024];
    int t = threadIdx.x;
    int base = t * 4;
    unsigned v[4], e[4], s = 0;
#pragma unroll
    for (int j = 0; j < 4; ++j) { v[j] = btot[base + j]; e[j] = s; s += v[j]; }
    sh[t] = s;
    __syncthreads();
    for (int off = 1; off < 1024; off <<= 1) {
        unsigned add = (t >= off) ? sh[t - off] : 0u;
        __syncthreads();
        sh[t] += add;
        __syncthreads();
    }
    unsigned excl = (t == 0) ? 0u : sh[t - 1];
#pragma unroll
    for (int j = 0; j < 4; ++j) btot[base + j] = excl + e[j];
    if (t == 1023) *nuq = sh[1023];
}

// Second flag pass: wprefix[word] = #occupied codes before this word
// (sequential 4.2MB write). Per occupied code: write decoded coords at row
// rank; zero outF rows with count>=2 (singletons get plain stores later).
__global__ void scan_write(const unsigned* __restrict__ cnt8,
                           const unsigned* __restrict__ btot,
                           unsigned* __restrict__ wprefix,
                           f4* __restrict__ outF4,
                           f4* __restrict__ outC4) {
    __shared__ unsigned sh[256];
    int t = threadIdx.x;
    int widx = blockIdx.x * 256 + t;
    unsigned w = cnt8[widx];
    unsigned c4[4] = {w & 0xFFu, (w >> 8) & 0xFFu, (w >> 16) & 0xFFu, w >> 24};
    unsigned e[4], s = 0;
#pragma unroll
    for (int j = 0; j < 4; ++j) { e[j] = s; s += (c4[j] != 0); }
    sh[t] = s;
    __syncthreads();
    for (int off = 1; off < 256; off <<= 1) {
        unsigned add = (t >= off) ? sh[t - off] : 0u;
        __syncthreads();
        sh[t] += add;
        __syncthreads();
    }
    unsigned texcl = ((t == 0) ? 0u : sh[t - 1]) + btot[blockIdx.x];
    wprefix[widx] = texcl;
    int cbase = widx * 4;
#pragma unroll
    for (int j = 0; j < 4; ++j) {
        if (c4[j]) {
            unsigned r = texcl + e[j];   // e[j] = within-word exclusive rank
            int code = cbase + j;
            f4 cv = {(float)(code >> 21), (float)((code >> 14) & 127),
                     (float)((code >> 7) & 127), (float)(code & 127)};
            outC4[r] = cv;
            if (c4[j] >= 2) {
                f4* row = outF4 + (size_t)r * 16;
                const f4 zz = {0.f, 0.f, 0.f, 0.f};
#pragma unroll
                for (int q = 0; q < 16; ++q) row[q] = zz;
            }
        }
    }
}

// Padding rows [n_uniq, n): zero feats, coords = -1.
__global__ void tail_pad(const unsigned* __restrict__ nuq,
                         f4* __restrict__ outF4,
                         f4* __restrict__ outC4, int n) {
    int r = blockIdx.x * 256 + threadIdx.x;
    if (r >= n || r < (int)*nuq) return;
    f4* row = outF4 + (size_t)r * 16;
    const f4 zz = {0.f, 0.f, 0.f, 0.f};
#pragma unroll
    for (int q = 0; q < 16; ++q) row[q] = zz;
    f4 mm = {-1.f, -1.f, -1.f, -1.f};
    outC4[r] = mm;
}

// Hot pass: 8 input rows per wave (quarter-wave = one 256B row, 2 batches).
// Sequential feats read; random 256B NT stores (fire-and-forget) for
// singleton rows, atomicAdd(v/cnt) for shared rows.
__global__ void scatter8(const f4* __restrict__ feats4,
                         const int* __restrict__ codes,
                         const unsigned* __restrict__ cnt8,
                         const unsigned* __restrict__ wprefix,
                         f4* __restrict__ outF4, int n) {
    int tid = blockIdx.x * 256 + threadIdx.x;
    int lane = threadIdx.x & 63;
    int wave = tid >> 6;
    int q = lane >> 4;
    int sub = lane & 15;
    int ib = wave * 8;

#pragma unroll
    for (int h = 0; h < 2; ++h) {
        int i = ib + h * 4 + q;
        if (i >= n) continue;
        int c = codes[i];
        unsigned w = cnt8[c >> 2];
        unsigned base = wprefix[c >> 2];
        int j = c & 3;
        unsigned cnt = (w >> (8 * j)) & 0xFFu;
        unsigned occ = 0;
        if (j > 0) occ += ((w & 0xFFu) != 0);
        if (j > 1) occ += (((w >> 8) & 0xFFu) != 0);
        if (j > 2) occ += (((w >> 16) & 0xFFu) != 0);
        unsigned r = base + occ;
        f4 v = feats4[(size_t)i * 16 + sub];
        f4* dst = outF4 + (size_t)r * 16 + sub;
        if (cnt == 1) {
            __builtin_nontemporal_store(v, dst);
        } else {
            float sc = 1.0f / (float)cnt;
            float* d = (float*)dst;
            atomicAdd(d + 0, v.x * sc);
            atomicAdd(d + 1, v.y * sc);
            atomicAdd(d + 2, v.z * sc);
            atomicAdd(d + 3, v.w * sc);
        }
    }
}

extern "C" void kernel_launch(void* const* d_in, const int* in_sizes, int n_in,
                              void* d_out, int out_size, void* d_ws, size_t ws_size,
                              hipStream_t stream) {
    const float* feats = (const float*)d_in[0];
    const int* coords = (const int*)d_in[1];
    const int n = in_sizes[1] / 4;   // N = 500000

    float* outF = (float*)d_out;
    f4* outF4 = (f4*)outF;
    f4* outC4 = (f4*)(outF + (size_t)n * 64);

    unsigned* cnt8 = (unsigned*)d_ws;              // NW u32 (4.19 MB)
    unsigned* btot = cnt8 + NW;                    // 4096
    unsigned* nuq = btot + HBLK;                   // 1
    int* codes = (int*)(nuq + 1);                  // n
    unsigned* wprefix = (unsigned*)(codes + n);    // NW u32 (4.19 MB)

    zero_cnt<<<2048, 256, 0, stream>>>((uint4*)cnt8);

    count_codes<<<(n + 255) / 256, 256, 0, stream>>>(coords, cnt8, codes, n);
    block_flag_sum<<<HBLK, 256, 0, stream>>>(cnt8, btot);
    scan_totals<<<1, 1024, 0, stream>>>(btot, nuq);
    scan_write<<<HBLK, 256, 0, stream>>>(cnt8, btot, wprefix, outF4, outC4);
    tail_pad<<<(n + 255) / 256, 256, 0, stream>>>(nuq, outF4, outC4, n);

    int waves = (n + 7) / 8;
    int blocks = (waves * 64 + 255) / 256;
    scatter8<<<blocks, 256, 0, stream>>>((const f4*)feats, codes, cnt8,
                                         wprefix, outF4, n);
}